// Round 3
// baseline (5389.680 us; speedup 1.0000x reference)
//
#include <hip/hip_runtime.h>

typedef unsigned short u16;
typedef __bf16 bf16x8 __attribute__((ext_vector_type(8)));
typedef u16 u16x8 __attribute__((ext_vector_type(8)));
typedef u16 u16x4 __attribute__((ext_vector_type(4)));
typedef float f32x4 __attribute__((ext_vector_type(4)));

__device__ __forceinline__ float bf2f(u16 v) {
    union { unsigned u; float f; } c; c.u = ((unsigned)v) << 16; return c.f;
}
__device__ __forceinline__ u16 f2bf(float f) {
    union { float f; unsigned u; } c; c.f = f;
    unsigned u = c.u;
    unsigned r = (u + 0x7fffu + ((u >> 16) & 1u)) >> 16;
    return (u16)r;
}

// ---------------------------------------------------------------------------
// fp32 -> bf16 elementwise convert (x -> xb). n must be multiple of 4*256.
// ---------------------------------------------------------------------------
__global__ __launch_bounds__(256) void cvt_kernel(const float* __restrict__ src,
                                                  u16* __restrict__ dst) {
    const long i = ((long)blockIdx.x * 256 + threadIdx.x) * 4;
    f32x4 v = *(const f32x4*)(src + i);
    u16x4 o;
#pragma unroll
    for (int r = 0; r < 4; r++) o[r] = f2bf(v[r]);
    *(u16x4*)(dst + i) = o;
}

// ---------------------------------------------------------------------------
// Weight transpose + cvt: src fp32 [1024,1024] (k,n) -> dst bf16 (n,k)
// ---------------------------------------------------------------------------
__global__ __launch_bounds__(256) void transpose_kernel(const float* __restrict__ src,
                                                        u16* __restrict__ dst) {
    __shared__ float tile[32][33];
    const int n0 = blockIdx.x * 32, k0 = blockIdx.y * 32;
    const int tx = threadIdx.x, ty = threadIdx.y;   // 32 x 8
#pragma unroll
    for (int i = 0; i < 32; i += 8)
        tile[ty + i][tx] = src[(long)(k0 + ty + i) * 1024 + n0 + tx];
    __syncthreads();
#pragma unroll
    for (int i = 0; i < 32; i += 8)
        dst[(long)(n0 + ty + i) * 1024 + k0 + tx] = f2bf(tile[tx][ty + i]);
}

// ---------------------------------------------------------------------------
// MFMA GEMM: C[M,N] = A[M,K](bf16) * BT[N,K](bf16)^T, fp32 accum.
// 128x128 tile, BK=32, 4 waves of 64x64 (4x4 of 16x16x32 mfma).
// F32OUT: 1 -> store fp32, 0 -> store bf16.
// ---------------------------------------------------------------------------
#define BK 32
#define LDK 40   // +8 pad: 80B row stride (16B aligned)

template <int F32OUT>
__global__ __launch_bounds__(256) void gemm_kernel(const u16* __restrict__ A,
                                                   const u16* __restrict__ BT,
                                                   void* __restrict__ Cv,
                                                   int M, int N, int K, int ldc) {
    __shared__ u16 As[128][LDK];
    __shared__ u16 Bs[128][LDK];
    const int tid  = threadIdx.x;
    const int lane = tid & 63;
    const int wave = tid >> 6;
    const int wm   = (wave >> 1) * 64;
    const int wn   = (wave & 1) * 64;
    const long m0  = (long)blockIdx.y * 128;
    const long n0  = (long)blockIdx.x * 128;

    const f32x4 zero = {0.f, 0.f, 0.f, 0.f};
    f32x4 acc[4][4];
#pragma unroll
    for (int i = 0; i < 4; i++)
#pragma unroll
        for (int j = 0; j < 4; j++) acc[i][j] = zero;

    const int r0 = tid >> 2;          // 0..63
    const int c0 = (tid & 3) * 8;
    const u16* Ag = A + (m0 + r0) * K + c0;
    const u16* Bg = BT + (n0 + r0) * K + c0;

    for (int k0 = 0; k0 < K; k0 += BK) {
        u16x8 a0 = *(const u16x8*)(Ag + k0);
        u16x8 a1 = *(const u16x8*)(Ag + (long)64 * K + k0);
        u16x8 b0 = *(const u16x8*)(Bg + k0);
        u16x8 b1 = *(const u16x8*)(Bg + (long)64 * K + k0);
        *(u16x8*)(&As[r0][c0])      = a0;
        *(u16x8*)(&As[r0 + 64][c0]) = a1;
        *(u16x8*)(&Bs[r0][c0])      = b0;
        *(u16x8*)(&Bs[r0 + 64][c0]) = b1;
        __syncthreads();
        const int qk = (lane >> 4) * 8;
        const int mr = lane & 15;
        bf16x8 af[4], bfr[4];
#pragma unroll
        for (int i = 0; i < 4; i++) af[i]  = *(const bf16x8*)(&As[wm + i * 16 + mr][qk]);
#pragma unroll
        for (int j = 0; j < 4; j++) bfr[j] = *(const bf16x8*)(&Bs[wn + j * 16 + mr][qk]);
#pragma unroll
        for (int i = 0; i < 4; i++)
#pragma unroll
            for (int j = 0; j < 4; j++)
                acc[i][j] = __builtin_amdgcn_mfma_f32_16x16x32_bf16(af[i], bfr[j], acc[i][j], 0, 0, 0);
        __syncthreads();
    }

    // C/D layout: col = lane&15, row = (lane>>4)*4 + reg   [m89-verified]
    const int cr = (lane >> 4) * 4;
    const int cc = lane & 15;
#pragma unroll
    for (int i = 0; i < 4; i++) {
#pragma unroll
        for (int j = 0; j < 4; j++) {
            const long m = m0 + wm + i * 16 + cr;
            const long n = n0 + wn + j * 16 + cc;
            if (F32OUT) {
                float* C = (float*)Cv;
#pragma unroll
                for (int r = 0; r < 4; r++) C[(m + r) * ldc + n] = acc[i][j][r];
            } else {
                u16* C = (u16*)Cv;
#pragma unroll
                for (int r = 0; r < 4; r++) C[(m + r) * ldc + n] = f2bf(acc[i][j][r]);
            }
        }
    }
}

// ---------------------------------------------------------------------------
// Fused: in-place L2-normalize q (x 1/16) and k per head; beta & dec per head.
// Y layout per row (3072 bf16 cols): [0,1024)=q, [1024,2048)=k, [2048,3072)=v.
// One block (1024 thr) per row (bt). xb is bf16; Wb/Wa/A_log/dt_bias fp32.
// ---------------------------------------------------------------------------
__global__ __launch_bounds__(1024) void norm_beta_kernel(
    const u16* __restrict__ xb, u16* __restrict__ Y,
    const float* __restrict__ Wb, const float* __restrict__ Wa,
    const float* __restrict__ A_log, const float* __restrict__ dt_bias,
    float* __restrict__ beta, float* __restrict__ dec) {
    const long row = blockIdx.x;
    const int c = threadIdx.x;     // 0..1023
    const int h = c >> 8;
    float qv = bf2f(Y[row * 3072 + c]);
    float kv = bf2f(Y[row * 3072 + 1024 + c]);
    float xv = bf2f(xb[row * 1024 + c]);
    float vals[10];
    vals[0] = qv * qv;
    vals[1] = kv * kv;
#pragma unroll
    for (int hh = 0; hh < 4; hh++) vals[2 + hh] = xv * Wb[c * 4 + hh];
#pragma unroll
    for (int hh = 0; hh < 4; hh++) vals[6 + hh] = xv * Wa[c * 4 + hh];
#pragma unroll
    for (int i = 0; i < 10; i++)
        for (int off = 32; off; off >>= 1) vals[i] += __shfl_xor(vals[i], off, 64);

    __shared__ float wred[16][10];
    __shared__ float sQ[4], sK[4];
    const int w = c >> 6;
    if ((c & 63) == 0) {
#pragma unroll
        for (int i = 0; i < 10; i++) wred[w][i] = vals[i];
    }
    __syncthreads();
    if (c < 4) {
        float s = wred[c * 4 + 0][0] + wred[c * 4 + 1][0] + wred[c * 4 + 2][0] + wred[c * 4 + 3][0];
        sQ[c] = rsqrtf(s + 1e-6f) * 0.0625f;       // l2norm then * DK^-0.5
    } else if (c < 8) {
        int hh = c - 4;
        float s = wred[hh * 4 + 0][1] + wred[hh * 4 + 1][1] + wred[hh * 4 + 2][1] + wred[hh * 4 + 3][1];
        sK[hh] = rsqrtf(s + 1e-6f);
    } else if (c < 12) {
        int hh = c - 8;
        float s = 0.f;
        for (int ww = 0; ww < 16; ww++) s += wred[ww][2 + hh];
        beta[row * 4 + hh] = 1.f / (1.f + expf(-s));
    } else if (c < 16) {
        int hh = c - 12;
        float s = 0.f;
        for (int ww = 0; ww < 16; ww++) s += wred[ww][6 + hh];
        float z = s + dt_bias[hh];
        float sp = (z > 0.f) ? (z + log1pf(expf(-z))) : log1pf(expf(z));
        dec[row * 4 + hh] = expf(-expf(A_log[hh]) * sp);
    }
    __syncthreads();
    Y[row * 3072 + c]        = f2bf(qv * sQ[h]);
    Y[row * 3072 + 1024 + c] = f2bf(kv * sK[h]);
}

// ---------------------------------------------------------------------------
// Exact gated delta-rule recurrence. State columns (dv) are independent:
// grid = 16 (b,h) x 16 dv-blocks of 16. Block 256 thr: dvi = tid&15,
// dkg = tid>>4; each thread holds S[dkg*16 .. +16)[dv] in 16 VGPRs.
// u = beta*(v - d*(k . S_prev)); S = d*S_prev + k u; o = q^T S.
// ---------------------------------------------------------------------------
__global__ __launch_bounds__(256) void recur_kernel(const u16* __restrict__ Y,
                                                    const float* __restrict__ beta,
                                                    const float* __restrict__ dec,
                                                    u16* __restrict__ O) {
    const int bh  = blockIdx.x & 15;
    const int dvb = blockIdx.x >> 4;
    const int b = bh >> 2, h = bh & 3;
    const int tid = threadIdx.x;
    const int dvi = tid & 15;
    const int dkg = tid >> 4;
    __shared__ float kL[256], qL[256], vL[16], uL[16], red[256];
    float S[16];
#pragma unroll
    for (int i = 0; i < 16; i++) S[i] = 0.f;
    const long obase = (long)b * 4096 * 1024;
    for (int t = 0; t < 4096; t++) {
        const long rb = ((long)b * 4096 + t) * 3072;
        kL[tid] = bf2f(Y[rb + 1024 + h * 256 + tid]);
        qL[tid] = bf2f(Y[rb + h * 256 + tid]);
        if (tid < 16) vL[tid] = bf2f(Y[rb + 2048 + h * 256 + dvb * 16 + tid]);
        const float bt = beta[((long)b * 4096 + t) * 4 + h];
        const float dt = dec[((long)b * 4096 + t) * 4 + h];
        __syncthreads();
        float kr[16];
        float p = 0.f;
#pragma unroll
        for (int i = 0; i < 16; i++) { kr[i] = kL[dkg * 16 + i]; p += kr[i] * S[i]; }
        red[tid] = p;
        __syncthreads();
        if (tid < 16) {
            float s = 0.f;
#pragma unroll
            for (int g = 0; g < 16; g++) s += red[g * 16 + tid];
            uL[tid] = bt * (vL[tid] - dt * s);
        }
        __syncthreads();
        const float u = uL[dvi];
        float op = 0.f;
#pragma unroll
        for (int i = 0; i < 16; i++) { S[i] = dt * S[i] + kr[i] * u; op += qL[dkg * 16 + i] * S[i]; }
        red[tid] = op;
        __syncthreads();
        if (tid < 16) {
            float s = 0.f;
#pragma unroll
            for (int g = 0; g < 16; g++) s += red[g * 16 + tid];
            O[obase + (long)t * 1024 + h * 256 + dvb * 16 + tid] = f2bf(s);
        }
    }
}

// ---------------------------------------------------------------------------
// Gated RMSNorm + SiLU; one block (256 thr) per (bt, h); reads O + G, writes
// og IN PLACE into G (same index per thread). norm_w fp32.
// ---------------------------------------------------------------------------
__global__ __launch_bounds__(256) void gate_norm_kernel(const u16* __restrict__ O,
                                                        u16* __restrict__ G,
                                                        const float* __restrict__ norm_w) {
    const long row = blockIdx.x >> 2;
    const int h = blockIdx.x & 3;
    const int dv = threadIdx.x;
    const long idx = row * 1024 + h * 256 + dv;
    float o = bf2f(O[idx]);
    float s = o * o;
#pragma unroll
    for (int off = 32; off; off >>= 1) s += __shfl_xor(s, off, 64);
    __shared__ float wsum[4];
    if ((dv & 63) == 0) wsum[dv >> 6] = s;
    __syncthreads();
    const float tot = wsum[0] + wsum[1] + wsum[2] + wsum[3];
    const float r = rsqrtf(tot * (1.f / 256.f) + 1e-5f);
    const float g = bf2f(G[idx]);
    const float val = o * r * norm_w[dv] * (g / (1.f + expf(-g)));
    G[idx] = f2bf(val);
}

// ---------------------------------------------------------------------------
extern "C" void kernel_launch(void* const* d_in, const int* in_sizes, int n_in,
                              void* d_out, int out_size, void* d_ws, size_t ws_size,
                              hipStream_t stream) {
    const float* x       = (const float*)d_in[0];
    const float* Wq      = (const float*)d_in[1];
    const float* Wk      = (const float*)d_in[2];
    const float* Wv      = (const float*)d_in[3];
    const float* Wb      = (const float*)d_in[4];
    const float* Wa      = (const float*)d_in[5];
    const float* A_log   = (const float*)d_in[6];
    const float* dt_bias = (const float*)d_in[7];
    const float* Wg      = (const float*)d_in[8];
    const float* norm_w  = (const float*)d_in[9];
    const float* Wo      = (const float*)d_in[10];

    // workspace ~171 MB (same footprint as round 2, which ran without fault)
    char* p = (char*)d_ws;
    u16*   WT   = (u16*)p;   p += (size_t)5120 * 1024 * 2;   // WqT|WkT|WvT|WgT|WoT bf16
    u16*   Y    = (u16*)p;   p += (size_t)16384 * 3072 * 2;  // q|k|v bf16
    u16*   G    = (u16*)p;   p += (size_t)16384 * 1024 * 2;  // gate, then og in place
    u16*   XO   = (u16*)p;   p += (size_t)16384 * 1024 * 2;  // xb (phase 1-3), O (phase 4-5)
    float* beta = (float*)p; p += (size_t)16384 * 4 * 4;
    float* dec  = (float*)p; p += (size_t)16384 * 4 * 4;

    // x fp32 -> bf16
    cvt_kernel<<<16384, 256, 0, stream>>>(x, XO);

    dim3 tb(32, 8), tg(32, 32);
    transpose_kernel<<<tg, tb, 0, stream>>>(Wq, WT + (size_t)0 * 1024 * 1024);
    transpose_kernel<<<tg, tb, 0, stream>>>(Wk, WT + (size_t)1 * 1024 * 1024);
    transpose_kernel<<<tg, tb, 0, stream>>>(Wv, WT + (size_t)2 * 1024 * 1024);
    transpose_kernel<<<tg, tb, 0, stream>>>(Wg, WT + (size_t)3 * 1024 * 1024);
    transpose_kernel<<<tg, tb, 0, stream>>>(Wo, WT + (size_t)4 * 1024 * 1024);

    // Y = xb @ [Wq|Wk|Wv]^T-stacked   (M=16384, N=3072, K=1024)
    gemm_kernel<0><<<dim3(3072 / 128, 16384 / 128), 256, 0, stream>>>(
        XO, WT, (void*)Y, 16384, 3072, 1024, 3072);
    // G = xb @ Wg  (N=1024)
    gemm_kernel<0><<<dim3(1024 / 128, 16384 / 128), 256, 0, stream>>>(
        XO, WT + (size_t)3072 * 1024, (void*)G, 16384, 1024, 1024, 1024);

    norm_beta_kernel<<<16384, 1024, 0, stream>>>(XO, Y, Wb, Wa, A_log, dt_bias, beta, dec);

    // xb is dead now; recur writes O into the same buffer (stream-ordered)
    recur_kernel<<<256, 256, 0, stream>>>(Y, beta, dec, XO);

    gate_norm_kernel<<<16384 * 4, 256, 0, stream>>>(XO, G, norm_w);

    // out = og @ Wo^T-stored   (M=16384, N=1024, K=1024), fp32 out
    gemm_kernel<1><<<dim3(1024 / 128, 16384 / 128), 256, 0, stream>>>(
        G, WT + (size_t)4096 * 1024, d_out, 16384, 1024, 1024, 1024);
}

// Round 4
// 2016.272 us; speedup vs baseline: 2.6731x; 2.6731x over previous
//
#include <hip/hip_runtime.h>

typedef unsigned short u16;
typedef __bf16 bf16x8 __attribute__((ext_vector_type(8)));
typedef u16 u16x8 __attribute__((ext_vector_type(8)));
typedef u16 u16x4 __attribute__((ext_vector_type(4)));
typedef float f32x4 __attribute__((ext_vector_type(4)));

__device__ __forceinline__ float bf2f(u16 v) {
    union { unsigned u; float f; } c; c.u = ((unsigned)v) << 16; return c.f;
}
__device__ __forceinline__ u16 f2bf(float f) {
    union { float f; unsigned u; } c; c.f = f;
    unsigned u = c.u;
    unsigned r = (u + 0x7fffu + ((u >> 16) & 1u)) >> 16;
    return (u16)r;
}

// MFMA fragment load: for LEFT operand from [m][k] row-major, or RIGHT operand
// from [n][k] row-major (i.e. right matrix transposed). Same lane mapping as the
// verified gemm_kernel: row = row0 + (lane&15), k = k0 + (lane>>4)*8 .. +8.
__device__ __forceinline__ bf16x8 ldfrag(const u16* base, int stride, int row0, int k0, int lane) {
    return *(const bf16x8*)(base + (size_t)(row0 + (lane & 15)) * stride + k0 + (lane >> 4) * 8);
}

// ---------------------------------------------------------------------------
// fp32 -> bf16 elementwise convert (x -> xb). n must be multiple of 4*256.
// ---------------------------------------------------------------------------
__global__ __launch_bounds__(256) void cvt_kernel(const float* __restrict__ src,
                                                  u16* __restrict__ dst) {
    const long i = ((long)blockIdx.x * 256 + threadIdx.x) * 4;
    f32x4 v = *(const f32x4*)(src + i);
    u16x4 o;
#pragma unroll
    for (int r = 0; r < 4; r++) o[r] = f2bf(v[r]);
    *(u16x4*)(dst + i) = o;
}

// ---------------------------------------------------------------------------
// Weight transpose + cvt: src fp32 [1024,1024] (k,n) -> dst bf16 (n,k)
// ---------------------------------------------------------------------------
__global__ __launch_bounds__(256) void transpose_kernel(const float* __restrict__ src,
                                                        u16* __restrict__ dst) {
    __shared__ float tile[32][33];
    const int n0 = blockIdx.x * 32, k0 = blockIdx.y * 32;
    const int tx = threadIdx.x, ty = threadIdx.y;   // 32 x 8
#pragma unroll
    for (int i = 0; i < 32; i += 8)
        tile[ty + i][tx] = src[(long)(k0 + ty + i) * 1024 + n0 + tx];
    __syncthreads();
#pragma unroll
    for (int i = 0; i < 32; i += 8)
        dst[(long)(n0 + ty + i) * 1024 + k0 + tx] = f2bf(tile[tx][ty + i]);
}

// ---------------------------------------------------------------------------
// MFMA GEMM: C[M,N] = A[M,K](bf16) * BT[N,K](bf16)^T, fp32 accum.
// 128x128 tile, BK=32, 4 waves of 64x64 (4x4 of 16x16x32 mfma).
// ---------------------------------------------------------------------------
#define LDK 40

template <int F32OUT>
__global__ __launch_bounds__(256) void gemm_kernel(const u16* __restrict__ A,
                                                   const u16* __restrict__ BT,
                                                   void* __restrict__ Cv,
                                                   int M, int N, int K, int ldc) {
    __shared__ u16 As[128][LDK];
    __shared__ u16 Bs[128][LDK];
    const int tid  = threadIdx.x;
    const int lane = tid & 63;
    const int wave = tid >> 6;
    const int wm   = (wave >> 1) * 64;
    const int wn   = (wave & 1) * 64;
    const long m0  = (long)blockIdx.y * 128;
    const long n0  = (long)blockIdx.x * 128;

    const f32x4 zero = {0.f, 0.f, 0.f, 0.f};
    f32x4 acc[4][4];
#pragma unroll
    for (int i = 0; i < 4; i++)
#pragma unroll
        for (int j = 0; j < 4; j++) acc[i][j] = zero;

    const int r0 = tid >> 2;
    const int c0 = (tid & 3) * 8;
    const u16* Ag = A + (m0 + r0) * K + c0;
    const u16* Bg = BT + (n0 + r0) * K + c0;

    for (int k0 = 0; k0 < K; k0 += 32) {
        u16x8 a0 = *(const u16x8*)(Ag + k0);
        u16x8 a1 = *(const u16x8*)(Ag + (long)64 * K + k0);
        u16x8 b0 = *(const u16x8*)(Bg + k0);
        u16x8 b1 = *(const u16x8*)(Bg + (long)64 * K + k0);
        *(u16x8*)(&As[r0][c0])      = a0;
        *(u16x8*)(&As[r0 + 64][c0]) = a1;
        *(u16x8*)(&Bs[r0][c0])      = b0;
        *(u16x8*)(&Bs[r0 + 64][c0]) = b1;
        __syncthreads();
        const int qk = (lane >> 4) * 8;
        const int mr = lane & 15;
        bf16x8 af[4], bfr[4];
#pragma unroll
        for (int i = 0; i < 4; i++) af[i]  = *(const bf16x8*)(&As[wm + i * 16 + mr][qk]);
#pragma unroll
        for (int j = 0; j < 4; j++) bfr[j] = *(const bf16x8*)(&Bs[wn + j * 16 + mr][qk]);
#pragma unroll
        for (int i = 0; i < 4; i++)
#pragma unroll
            for (int j = 0; j < 4; j++)
                acc[i][j] = __builtin_amdgcn_mfma_f32_16x16x32_bf16(af[i], bfr[j], acc[i][j], 0, 0, 0);
        __syncthreads();
    }

    const int cr = (lane >> 4) * 4;
    const int cc = lane & 15;
#pragma unroll
    for (int i = 0; i < 4; i++) {
#pragma unroll
        for (int j = 0; j < 4; j++) {
            const long m = m0 + wm + i * 16 + cr;
            const long n = n0 + wn + j * 16 + cc;
            if (F32OUT) {
                float* C = (float*)Cv;
#pragma unroll
                for (int r = 0; r < 4; r++) C[(m + r) * ldc + n] = acc[i][j][r];
            } else {
                u16* C = (u16*)Cv;
#pragma unroll
                for (int r = 0; r < 4; r++) C[(m + r) * ldc + n] = f2bf(acc[i][j][r]);
            }
        }
    }
}

// ---------------------------------------------------------------------------
// Fused: in-place L2-normalize q (x 1/16) and k per head; beta & dec per head.
// ---------------------------------------------------------------------------
__global__ __launch_bounds__(1024) void norm_beta_kernel(
    const u16* __restrict__ xb, u16* __restrict__ Y,
    const float* __restrict__ Wb, const float* __restrict__ Wa,
    const float* __restrict__ A_log, const float* __restrict__ dt_bias,
    float* __restrict__ beta, float* __restrict__ dec) {
    const long row = blockIdx.x;
    const int c = threadIdx.x;
    const int h = c >> 8;
    float qv = bf2f(Y[row * 3072 + c]);
    float kv = bf2f(Y[row * 3072 + 1024 + c]);
    float xv = bf2f(xb[row * 1024 + c]);
    float vals[10];
    vals[0] = qv * qv;
    vals[1] = kv * kv;
#pragma unroll
    for (int hh = 0; hh < 4; hh++) vals[2 + hh] = xv * Wb[c * 4 + hh];
#pragma unroll
    for (int hh = 0; hh < 4; hh++) vals[6 + hh] = xv * Wa[c * 4 + hh];
#pragma unroll
    for (int i = 0; i < 10; i++)
        for (int off = 32; off; off >>= 1) vals[i] += __shfl_xor(vals[i], off, 64);

    __shared__ float wred[16][10];
    __shared__ float sQ[4], sK[4];
    const int w = c >> 6;
    if ((c & 63) == 0) {
#pragma unroll
        for (int i = 0; i < 10; i++) wred[w][i] = vals[i];
    }
    __syncthreads();
    if (c < 4) {
        float s = wred[c * 4 + 0][0] + wred[c * 4 + 1][0] + wred[c * 4 + 2][0] + wred[c * 4 + 3][0];
        sQ[c] = rsqrtf(s + 1e-6f) * 0.0625f;
    } else if (c < 8) {
        int hh = c - 4;
        float s = wred[hh * 4 + 0][1] + wred[hh * 4 + 1][1] + wred[hh * 4 + 2][1] + wred[hh * 4 + 3][1];
        sK[hh] = rsqrtf(s + 1e-6f);
    } else if (c < 12) {
        int hh = c - 8;
        float s = 0.f;
        for (int ww = 0; ww < 16; ww++) s += wred[ww][2 + hh];
        beta[row * 4 + hh] = 1.f / (1.f + expf(-s));
    } else if (c < 16) {
        int hh = c - 12;
        float s = 0.f;
        for (int ww = 0; ww < 16; ww++) s += wred[ww][6 + hh];
        float z = s + dt_bias[hh];
        float sp = (z > 0.f) ? (z + log1pf(expf(-z))) : log1pf(expf(z));
        dec[row * 4 + hh] = expf(-expf(A_log[hh]) * sp);
    }
    __syncthreads();
    Y[row * 3072 + c]        = f2bf(qv * sQ[h]);
    Y[row * 3072 + 1024 + c] = f2bf(kv * sK[h]);
}

// ---------------------------------------------------------------------------
// Chunked gated delta rule. Grid 64 = (b:4, h:4, dvs:4); block 256 (4 waves).
// Per chunk (L=64): gamma prefix; G_k=KK^T, G_q=QK^T; A/M matrices;
// (I+A)U = beta*V - diag(beta*gamma) K S0  solved via nilpotent doubling;
// O = diag(gamma) Q S0 + M U;  S <- gamma_L S + K'^T U.
// State [64dv x 256dk] fp32 in accumulators; bf16 transposed copy in LDS.
// ---------------------------------------------------------------------------
__global__ __launch_bounds__(256) void chunk_kernel(const u16* __restrict__ Y,
                                                    const float* __restrict__ beta,
                                                    const float* __restrict__ dec,
                                                    u16* __restrict__ Ob) {
    __shared__ __attribute__((aligned(16))) u16 lds[78336];
    __shared__ float sf[320];   // [0]=lg2, [64]=gam, [128]=beta*gam, [192]=beta, [256]=kscale
    u16* KS = lds;              // 64 x 264  (K chunk, [t][dk])
    u16* QS = lds + 16896;      // 64 x 264  (Q chunk)
    u16* KT = lds + 33792;      // 256 x 72  (K^T * kscale, [dk][t])
    u16* ST = lds + 52224;      // 64 x 264  (state^T bf16, [dv][dk])
    u16* AM = lds + 69120;      // 64 x 72   (A matrix, [t][s])
    u16* MM = lds + 73728;      // 64 x 72   (M matrix, [t][s])
    // unions (valid after the P phase, when KS/QS are dead):
    u16* Tm  = lds;             // 64 x 72   (T = running inverse, [t][s])
    u16* AMT = lds + 4608;      // 64 x 72   (A^T, [s][t])
    u16* MP  = lds + 9216;      // 64 x 72   (N^(2^j), [t][s])
    u16* RHST= lds + 16896;     // 64 x 72   (RHS^T, [dv][t])
    u16* UT  = lds + 21504;     // 64 x 72   (U^T, [dv][t])
    u16* MPT = lds + 26112;     // 64 x 72   (N^(2^j) transposed, [s][t])

    const int bx = blockIdx.x;
    const int b = bx >> 4, h = (bx >> 2) & 3, dvs = bx & 3;
    const int tid = threadIdx.x, lane = tid & 63, wv = tid >> 6;
    const int quad = lane >> 4, l15 = lane & 15;
    const int tld = tid >> 2, seg = tid & 3;

    const f32x4 z4 = {0.f, 0.f, 0.f, 0.f};
    f32x4 Sacc[4][4];   // state: dv-tile i (16), dk-tile j within this wave's 64-dk slice
#pragma unroll
    for (int i = 0; i < 4; i++)
#pragma unroll
        for (int j = 0; j < 4; j++) Sacc[i][j] = z4;
    for (int i = tid; i < 64 * 264; i += 256) ST[i] = 0;
    __syncthreads();

#pragma unroll 1
    for (int c = 0; c < 64; ++c) {
        const long bt0 = (long)b * 4096 + c * 64;
        // ---- phase 1: stage K,Q into LDS; V into regs; gamma prefix ----
        {
            const long rb = (bt0 + tld) * 3072 + h * 256 + seg * 64;
#pragma unroll
            for (int i = 0; i < 8; i++) {
                *(u16x8*)&KS[tld * 264 + seg * 64 + i * 8] = *(const u16x8*)&Y[rb + 1024 + i * 8];
                *(u16x8*)&QS[tld * 264 + seg * 64 + i * 8] = *(const u16x8*)&Y[rb + i * 8];
            }
        }
        float vreg[4][4];
#pragma unroll
        for (int j = 0; j < 4; j++)
#pragma unroll
            for (int r = 0; r < 4; r++) {
                const int t_ = 16 * wv + quad * 4 + r;
                vreg[j][r] = bf2f(Y[(bt0 + t_) * 3072 + 2048 + h * 256 + dvs * 64 + j * 16 + l15]);
            }
        if (wv == 0) {
            float d   = dec [(bt0 + lane) * 4 + h];
            float bt_ = beta[(bt0 + lane) * 4 + h];
            float lg = log2f(fmaxf(d, 1e-30f));
#pragma unroll
            for (int off = 1; off < 64; off <<= 1) {
                float o = __shfl_up(lg, off, 64);
                if (lane >= off) lg += o;
            }
            float lgL = __shfl(lg, 63, 64);
            float g = exp2f(lg);
            sf[lane] = lg; sf[64 + lane] = g; sf[128 + lane] = bt_ * g;
            sf[192 + lane] = bt_; sf[256 + lane] = exp2f(lgL - lg);
        }
        __syncthreads();   // B1

        // ---- phase 1.5: build KT[dk][t] = kscale[t] * K[t][dk] ----
        {
            const float ksc = sf[256 + tld];
#pragma unroll
            for (int i = 0; i < 8; i++) {
                u16x8 kv = *(const u16x8*)&KS[tld * 264 + seg * 64 + i * 8];
#pragma unroll
                for (int jj = 0; jj < 8; jj++)
                    KT[(seg * 64 + i * 8 + jj) * 72 + tld] = f2bf(ksc * bf2f(kv[jj]));
            }
        }

        // ---- phase 2: G_k (waves 0,1), G_q (waves 2,3) -> AM / MM ----
        {
            const u16* Ab = (wv < 2) ? KS : QS;
            const int mb = (wv & 1) * 32;
            f32x4 g[2][4];
#pragma unroll
            for (int mi = 0; mi < 2; mi++)
#pragma unroll
                for (int sj = 0; sj < 4; sj++) g[mi][sj] = z4;
#pragma unroll 2
            for (int k0 = 0; k0 < 256; k0 += 32) {
                bf16x8 bfr[4];
#pragma unroll
                for (int sj = 0; sj < 4; sj++) bfr[sj] = ldfrag(KS, 264, sj * 16, k0, lane);
#pragma unroll
                for (int mi = 0; mi < 2; mi++) {
                    bf16x8 af = ldfrag(Ab, 264, mb + mi * 16, k0, lane);
#pragma unroll
                    for (int sj = 0; sj < 4; sj++)
                        g[mi][sj] = __builtin_amdgcn_mfma_f32_16x16x32_bf16(af, bfr[sj], g[mi][sj], 0, 0, 0);
                }
            }
#pragma unroll
            for (int mi = 0; mi < 2; mi++)
#pragma unroll
                for (int sj = 0; sj < 4; sj++)
#pragma unroll
                    for (int r = 0; r < 4; r++) {
                        const int t_ = mb + mi * 16 + quad * 4 + r, s_ = sj * 16 + l15;
                        if (wv < 2)
                            AM[t_ * 72 + s_] = (s_ < t_) ? f2bf(sf[192 + t_] * exp2f(sf[t_] - sf[s_]) * g[mi][sj][r]) : (u16)0;
                        else
                            MM[t_ * 72 + s_] = (s_ <= t_) ? f2bf(exp2f(sf[t_] - sf[s_]) * g[mi][sj][r]) : (u16)0;
                    }
        }
        __syncthreads();   // B3

        // ---- phase 3: P_k = K S0, P_q = Q S0 (wave owns t-rows 16wv..) ----
        f32x4 pk[4], pq[4], oacc[4], rhsv[4];
#pragma unroll
        for (int j = 0; j < 4; j++) { pk[j] = z4; pq[j] = z4; }
#pragma unroll 2
        for (int k0 = 0; k0 < 256; k0 += 32) {
            bf16x8 sfr[4];
#pragma unroll
            for (int j = 0; j < 4; j++) sfr[j] = ldfrag(ST, 264, j * 16, k0, lane);
            bf16x8 ak = ldfrag(KS, 264, 16 * wv, k0, lane);
            bf16x8 aq = ldfrag(QS, 264, 16 * wv, k0, lane);
#pragma unroll
            for (int j = 0; j < 4; j++) {
                pk[j] = __builtin_amdgcn_mfma_f32_16x16x32_bf16(ak, sfr[j], pk[j], 0, 0, 0);
                pq[j] = __builtin_amdgcn_mfma_f32_16x16x32_bf16(aq, sfr[j], pq[j], 0, 0, 0);
            }
        }
#pragma unroll
        for (int j = 0; j < 4; j++)
#pragma unroll
            for (int r = 0; r < 4; r++) {
                const int t_ = 16 * wv + quad * 4 + r;
                rhsv[j][r] = sf[192 + t_] * vreg[j][r] - sf[128 + t_] * pk[j][r];
                oacc[j][r] = sf[64 + t_] * pq[j][r];
            }
        __syncthreads();   // B4 — all KS/QS reads done; unions now writable

        // ---- write RHS^T; r0: T = I - A, A^T ----
#pragma unroll
        for (int j = 0; j < 4; j++)
#pragma unroll
            for (int r = 0; r < 4; r++)
                RHST[(j * 16 + l15) * 72 + (16 * wv + quad * 4 + r)] = f2bf(rhsv[j][r]);
        {
            const int t_ = tid >> 2;
#pragma unroll
            for (int i = 0; i < 16; i++) {
                const int s_ = (tid & 3) * 16 + i;
                const u16 a = AM[t_ * 72 + s_];
                Tm[t_ * 72 + s_] = (t_ == s_) ? (u16)0x3F80 : (u16)(a ^ 0x8000);
                AMT[s_ * 72 + t_] = a;
            }
        }
        __syncthreads();   // B5

        // ---- solve r1: Mp = N*N ----
        {
            f32x4 sq[4];
#pragma unroll
            for (int sj = 0; sj < 4; sj++) sq[sj] = z4;
#pragma unroll
            for (int k0 = 0; k0 < 64; k0 += 32) {
                bf16x8 a = ldfrag(AM, 72, 16 * wv, k0, lane);
#pragma unroll
                for (int sj = 0; sj < 4; sj++) {
                    bf16x8 bb = ldfrag(AMT, 72, sj * 16, k0, lane);
                    sq[sj] = __builtin_amdgcn_mfma_f32_16x16x32_bf16(a, bb, sq[sj], 0, 0, 0);
                }
            }
#pragma unroll
            for (int sj = 0; sj < 4; sj++)
#pragma unroll
                for (int r = 0; r < 4; r++) {
                    const int t_ = 16 * wv + quad * 4 + r, s_ = sj * 16 + l15;
                    const u16 vbf = f2bf(sq[sj][r]);
                    MP[t_ * 72 + s_] = vbf;
                    MPT[s_ * 72 + t_] = vbf;
                }
            __syncthreads();   // B6
        }

        // ---- solve fused rounds: T += T*Mp ; Mp <- Mp*Mp (skip on last) ----
#pragma unroll 1
        for (int jj = 0; jj < 5; jj++) {
            const bool last = (jj == 4);
            f32x4 pp[4], sq[4];
#pragma unroll
            for (int sj = 0; sj < 4; sj++) {
                sq[sj] = z4;
#pragma unroll
                for (int r = 0; r < 4; r++)
                    pp[sj][r] = bf2f(Tm[(16 * wv + quad * 4 + r) * 72 + sj * 16 + l15]);
            }
#pragma unroll
            for (int k0 = 0; k0 < 64; k0 += 32) {
                bf16x8 at = ldfrag(Tm, 72, 16 * wv, k0, lane);
                bf16x8 am = ldfrag(MP, 72, 16 * wv, k0, lane);
#pragma unroll
                for (int sj = 0; sj < 4; sj++) {
                    bf16x8 bb = ldfrag(MPT, 72, sj * 16, k0, lane);
                    pp[sj] = __builtin_amdgcn_mfma_f32_16x16x32_bf16(at, bb, pp[sj], 0, 0, 0);
                    if (!last) sq[sj] = __builtin_amdgcn_mfma_f32_16x16x32_bf16(am, bb, sq[sj], 0, 0, 0);
                }
            }
            __syncthreads();   // reads done
#pragma unroll
            for (int sj = 0; sj < 4; sj++)
#pragma unroll
                for (int r = 0; r < 4; r++) {
                    const int t_ = 16 * wv + quad * 4 + r, s_ = sj * 16 + l15;
                    Tm[t_ * 72 + s_] = f2bf(pp[sj][r]);
                    if (!last) {
                        const u16 vbf = f2bf(sq[sj][r]);
                        MP[t_ * 72 + s_] = vbf;
                        MPT[s_ * 72 + t_] = vbf;
                    }
                }
            __syncthreads();
        }

        // ---- U = T * RHS -> UT ----
        {
            f32x4 uu[4];
#pragma unroll
            for (int sj = 0; sj < 4; sj++) uu[sj] = z4;
#pragma unroll
            for (int k0 = 0; k0 < 64; k0 += 32) {
                bf16x8 at = ldfrag(Tm, 72, 16 * wv, k0, lane);
#pragma unroll
                for (int sj = 0; sj < 4; sj++) {
                    bf16x8 bb = ldfrag(RHST, 72, sj * 16, k0, lane);
                    uu[sj] = __builtin_amdgcn_mfma_f32_16x16x32_bf16(at, bb, uu[sj], 0, 0, 0);
                }
            }
#pragma unroll
            for (int sj = 0; sj < 4; sj++)
#pragma unroll
                for (int r = 0; r < 4; r++)
                    UT[(sj * 16 + l15) * 72 + (16 * wv + quad * 4 + r)] = f2bf(uu[sj][r]);
            __syncthreads();   // B8
        }

        // ---- O = oacc + M*U -> global ; state update ; write ST ----
        {
#pragma unroll
            for (int k0 = 0; k0 < 64; k0 += 32) {
                bf16x8 am = ldfrag(MM, 72, 16 * wv, k0, lane);
#pragma unroll
                for (int sj = 0; sj < 4; sj++) {
                    bf16x8 bb = ldfrag(UT, 72, sj * 16, k0, lane);
                    oacc[sj] = __builtin_amdgcn_mfma_f32_16x16x32_bf16(am, bb, oacc[sj], 0, 0, 0);
                }
            }
#pragma unroll
            for (int sj = 0; sj < 4; sj++)
#pragma unroll
                for (int r = 0; r < 4; r++) {
                    const int t_ = 16 * wv + quad * 4 + r;
                    Ob[(bt0 + t_) * 1024 + h * 256 + dvs * 64 + sj * 16 + l15] = f2bf(oacc[sj][r]);
                }
            const float gL = sf[64 + 63];
#pragma unroll
            for (int i = 0; i < 4; i++)
#pragma unroll
                for (int j = 0; j < 4; j++) Sacc[i][j] *= gL;
#pragma unroll
            for (int k0 = 0; k0 < 64; k0 += 32) {
                bf16x8 au[4], bk[4];
#pragma unroll
                for (int i = 0; i < 4; i++) au[i] = ldfrag(UT, 72, i * 16, k0, lane);
#pragma unroll
                for (int j = 0; j < 4; j++) bk[j] = ldfrag(KT, 72, wv * 64 + j * 16, k0, lane);
#pragma unroll
                for (int i = 0; i < 4; i++)
#pragma unroll
                    for (int j = 0; j < 4; j++)
                        Sacc[i][j] = __builtin_amdgcn_mfma_f32_16x16x32_bf16(au[i], bk[j], Sacc[i][j], 0, 0, 0);
            }
#pragma unroll
            for (int i = 0; i < 4; i++)
#pragma unroll
                for (int j = 0; j < 4; j++)
#pragma unroll
                    for (int r = 0; r < 4; r++)
                        ST[(i * 16 + quad * 4 + r) * 264 + wv * 64 + j * 16 + l15] = f2bf(Sacc[i][j][r]);
            __syncthreads();   // B9 — next chunk may read ST / overwrite unions
        }
    }
}

// ---------------------------------------------------------------------------
// Gated RMSNorm + SiLU; writes og IN PLACE into G.
// ---------------------------------------------------------------------------
__global__ __launch_bounds__(256) void gate_norm_kernel(const u16* __restrict__ O,
                                                        u16* __restrict__ G,
                                                        const float* __restrict__ norm_w) {
    const long row = blockIdx.x >> 2;
    const int h = blockIdx.x & 3;
    const int dv = threadIdx.x;
    const long idx = row * 1024 + h * 256 + dv;
    float o = bf2f(O[idx]);
    float s = o * o;
#pragma unroll
    for (int off = 32; off; off >>= 1) s += __shfl_xor(s, off, 64);
    __shared__ float wsum[4];
    if ((dv & 63) == 0) wsum[dv >> 6] = s;
    __syncthreads();
    const float tot = wsum[0] + wsum[1] + wsum[2] + wsum[3];
    const float r = rsqrtf(tot * (1.f / 256.f) + 1e-5f);
    const float g = bf2f(G[idx]);
    const float val = o * r * norm_w[dv] * (g / (1.f + expf(-g)));
    G[idx] = f2bf(val);
}

// ---------------------------------------------------------------------------
extern "C" void kernel_launch(void* const* d_in, const int* in_sizes, int n_in,
                              void* d_out, int out_size, void* d_ws, size_t ws_size,
                              hipStream_t stream) {
    const float* x       = (const float*)d_in[0];
    const float* Wq      = (const float*)d_in[1];
    const float* Wk      = (const float*)d_in[2];
    const float* Wv      = (const float*)d_in[3];
    const float* Wb      = (const float*)d_in[4];
    const float* Wa      = (const float*)d_in[5];
    const float* A_log   = (const float*)d_in[6];
    const float* dt_bias = (const float*)d_in[7];
    const float* Wg      = (const float*)d_in[8];
    const float* norm_w  = (const float*)d_in[9];
    const float* Wo      = (const float*)d_in[10];

    char* p = (char*)d_ws;
    u16*   WT   = (u16*)p;   p += (size_t)5120 * 1024 * 2;
    u16*   Y    = (u16*)p;   p += (size_t)16384 * 3072 * 2;
    u16*   G    = (u16*)p;   p += (size_t)16384 * 1024 * 2;
    u16*   XO   = (u16*)p;   p += (size_t)16384 * 1024 * 2;
    float* beta = (float*)p; p += (size_t)16384 * 4 * 4;
    float* dec  = (float*)p; p += (size_t)16384 * 4 * 4;

    cvt_kernel<<<16384, 256, 0, stream>>>(x, XO);

    dim3 tb(32, 8), tg(32, 32);
    transpose_kernel<<<tg, tb, 0, stream>>>(Wq, WT + (size_t)0 * 1024 * 1024);
    transpose_kernel<<<tg, tb, 0, stream>>>(Wk, WT + (size_t)1 * 1024 * 1024);
    transpose_kernel<<<tg, tb, 0, stream>>>(Wv, WT + (size_t)2 * 1024 * 1024);
    transpose_kernel<<<tg, tb, 0, stream>>>(Wg, WT + (size_t)3 * 1024 * 1024);
    transpose_kernel<<<tg, tb, 0, stream>>>(Wo, WT + (size_t)4 * 1024 * 1024);

    gemm_kernel<0><<<dim3(3072 / 128, 16384 / 128), 256, 0, stream>>>(
        XO, WT, (void*)Y, 16384, 3072, 1024, 3072);
    gemm_kernel<0><<<dim3(1024 / 128, 16384 / 128), 256, 0, stream>>>(
        XO, WT + (size_t)3072 * 1024, (void*)G, 16384, 1024, 1024, 1024);

    norm_beta_kernel<<<16384, 1024, 0, stream>>>(XO, Y, Wb, Wa, A_log, dt_bias, beta, dec);

    // xb dead; chunk_kernel writes O into the same buffer
    chunk_kernel<<<64, 256, 0, stream>>>(Y, beta, dec, XO);

    gate_norm_kernel<<<16384 * 4, 256, 0, stream>>>(XO, G, norm_w);

    gemm_kernel<1><<<dim3(1024 / 128, 16384 / 128), 256, 0, stream>>>(
        G, WT + (size_t)4096 * 1024, d_out, 16384, 1024, 1024, 1024);
}

// Round 5
// 1157.948 us; speedup vs baseline: 4.6545x; 1.7412x over previous
//
#include <hip/hip_runtime.h>

typedef unsigned short u16;
typedef __bf16 bf16x8 __attribute__((ext_vector_type(8)));
typedef u16 u16x8 __attribute__((ext_vector_type(8)));
typedef u16 u16x4 __attribute__((ext_vector_type(4)));
typedef float f32x4 __attribute__((ext_vector_type(4)));

__device__ __forceinline__ float bf2f(u16 v) {
    union { unsigned u; float f; } c; c.u = ((unsigned)v) << 16; return c.f;
}
__device__ __forceinline__ u16 f2bf(float f) {
    union { float f; unsigned u; } c; c.f = f;
    unsigned u = c.u;
    unsigned r = (u + 0x7fffu + ((u >> 16) & 1u)) >> 16;
    return (u16)r;
}

// MFMA fragment load (works for LDS or global pointers): LEFT operand from
// [m][k] row-major, or RIGHT operand from [n][k] row-major.
// row = row0 + (lane&15), k = k0 + (lane>>4)*8 .. +8.
__device__ __forceinline__ bf16x8 ldfrag(const u16* base, int stride, int row0, int k0, int lane) {
    return *(const bf16x8*)(base + (size_t)(row0 + (lane & 15)) * stride + k0 + (lane >> 4) * 8);
}

// ---------------------------------------------------------------------------
// fp32 -> bf16 elementwise convert
// ---------------------------------------------------------------------------
__global__ __launch_bounds__(256) void cvt_kernel(const float* __restrict__ src,
                                                  u16* __restrict__ dst) {
    const long i = ((long)blockIdx.x * 256 + threadIdx.x) * 4;
    f32x4 v = *(const f32x4*)(src + i);
    u16x4 o;
#pragma unroll
    for (int r = 0; r < 4; r++) o[r] = f2bf(v[r]);
    *(u16x4*)(dst + i) = o;
}

// ---------------------------------------------------------------------------
// Weight transpose + cvt: src fp32 [1024,1024] (k,n) -> dst bf16 (n,k)
// ---------------------------------------------------------------------------
__global__ __launch_bounds__(256) void transpose_kernel(const float* __restrict__ src,
                                                        u16* __restrict__ dst) {
    __shared__ float tile[32][33];
    const int n0 = blockIdx.x * 32, k0 = blockIdx.y * 32;
    const int tx = threadIdx.x, ty = threadIdx.y;   // 32 x 8
#pragma unroll
    for (int i = 0; i < 32; i += 8)
        tile[ty + i][tx] = src[(long)(k0 + ty + i) * 1024 + n0 + tx];
    __syncthreads();
#pragma unroll
    for (int i = 0; i < 32; i += 8)
        dst[(long)(n0 + ty + i) * 1024 + k0 + tx] = f2bf(tile[tx][ty + i]);
}

// ---------------------------------------------------------------------------
// MFMA GEMM: C[M,N] = A[M,K](bf16) * BT[N,K](bf16)^T, fp32 accum.
// ---------------------------------------------------------------------------
#define LDK 40

template <int F32OUT>
__global__ __launch_bounds__(256) void gemm_kernel(const u16* __restrict__ A,
                                                   const u16* __restrict__ BT,
                                                   void* __restrict__ Cv,
                                                   int M, int N, int K, int ldc) {
    __shared__ u16 As[128][LDK];
    __shared__ u16 Bs[128][LDK];
    const int tid  = threadIdx.x;
    const int lane = tid & 63;
    const int wave = tid >> 6;
    const int wm   = (wave >> 1) * 64;
    const int wn   = (wave & 1) * 64;
    const long m0  = (long)blockIdx.y * 128;
    const long n0  = (long)blockIdx.x * 128;

    const f32x4 zero = {0.f, 0.f, 0.f, 0.f};
    f32x4 acc[4][4];
#pragma unroll
    for (int i = 0; i < 4; i++)
#pragma unroll
        for (int j = 0; j < 4; j++) acc[i][j] = zero;

    const int r0 = tid >> 2;
    const int c0 = (tid & 3) * 8;
    const u16* Ag = A + (m0 + r0) * K + c0;
    const u16* Bg = BT + (n0 + r0) * K + c0;

    for (int k0 = 0; k0 < K; k0 += 32) {
        u16x8 a0 = *(const u16x8*)(Ag + k0);
        u16x8 a1 = *(const u16x8*)(Ag + (long)64 * K + k0);
        u16x8 b0 = *(const u16x8*)(Bg + k0);
        u16x8 b1 = *(const u16x8*)(Bg + (long)64 * K + k0);
        *(u16x8*)(&As[r0][c0])      = a0;
        *(u16x8*)(&As[r0 + 64][c0]) = a1;
        *(u16x8*)(&Bs[r0][c0])      = b0;
        *(u16x8*)(&Bs[r0 + 64][c0]) = b1;
        __syncthreads();
        const int qk = (lane >> 4) * 8;
        const int mr = lane & 15;
        bf16x8 af[4], bfr[4];
#pragma unroll
        for (int i = 0; i < 4; i++) af[i]  = *(const bf16x8*)(&As[wm + i * 16 + mr][qk]);
#pragma unroll
        for (int j = 0; j < 4; j++) bfr[j] = *(const bf16x8*)(&Bs[wn + j * 16 + mr][qk]);
#pragma unroll
        for (int i = 0; i < 4; i++)
#pragma unroll
            for (int j = 0; j < 4; j++)
                acc[i][j] = __builtin_amdgcn_mfma_f32_16x16x32_bf16(af[i], bfr[j], acc[i][j], 0, 0, 0);
        __syncthreads();
    }

    const int cr = (lane >> 4) * 4;
    const int cc = lane & 15;
#pragma unroll
    for (int i = 0; i < 4; i++) {
#pragma unroll
        for (int j = 0; j < 4; j++) {
            const long m = m0 + wm + i * 16 + cr;
            const long n = n0 + wn + j * 16 + cc;
            if (F32OUT) {
                float* C = (float*)Cv;
#pragma unroll
                for (int r = 0; r < 4; r++) C[(m + r) * ldc + n] = acc[i][j][r];
            } else {
                u16* C = (u16*)Cv;
#pragma unroll
                for (int r = 0; r < 4; r++) C[(m + r) * ldc + n] = f2bf(acc[i][j][r]);
            }
        }
    }
}

// ---------------------------------------------------------------------------
// Same GEMM but A operand is fp32 in global (converted to bf16 at staging).
// ---------------------------------------------------------------------------
__global__ __launch_bounds__(256) void gemm_a32_kernel(const float* __restrict__ A,
                                                       const u16* __restrict__ BT,
                                                       u16* __restrict__ C,
                                                       int M, int N, int K, int ldc) {
    __shared__ u16 As[128][LDK];
    __shared__ u16 Bs[128][LDK];
    const int tid  = threadIdx.x;
    const int lane = tid & 63;
    const int wave = tid >> 6;
    const int wm   = (wave >> 1) * 64;
    const int wn   = (wave & 1) * 64;
    const long m0  = (long)blockIdx.y * 128;
    const long n0  = (long)blockIdx.x * 128;

    const f32x4 zero = {0.f, 0.f, 0.f, 0.f};
    f32x4 acc[4][4];
#pragma unroll
    for (int i = 0; i < 4; i++)
#pragma unroll
        for (int j = 0; j < 4; j++) acc[i][j] = zero;

    const int r0 = tid >> 2;
    const int c0 = (tid & 3) * 8;
    const float* Ag = A + (m0 + r0) * K + c0;
    const u16* Bg = BT + (n0 + r0) * K + c0;

    for (int k0 = 0; k0 < K; k0 += 32) {
        f32x4 af0 = *(const f32x4*)(Ag + k0);
        f32x4 af1 = *(const f32x4*)(Ag + k0 + 4);
        f32x4 ag0 = *(const f32x4*)(Ag + (long)64 * K + k0);
        f32x4 ag1 = *(const f32x4*)(Ag + (long)64 * K + k0 + 4);
        u16x8 b0 = *(const u16x8*)(Bg + k0);
        u16x8 b1 = *(const u16x8*)(Bg + (long)64 * K + k0);
        u16x8 a0, a1;
#pragma unroll
        for (int r = 0; r < 4; r++) {
            a0[r] = f2bf(af0[r]); a0[r + 4] = f2bf(af1[r]);
            a1[r] = f2bf(ag0[r]); a1[r + 4] = f2bf(ag1[r]);
        }
        *(u16x8*)(&As[r0][c0])      = a0;
        *(u16x8*)(&As[r0 + 64][c0]) = a1;
        *(u16x8*)(&Bs[r0][c0])      = b0;
        *(u16x8*)(&Bs[r0 + 64][c0]) = b1;
        __syncthreads();
        const int qk = (lane >> 4) * 8;
        const int mr = lane & 15;
        bf16x8 af[4], bfr[4];
#pragma unroll
        for (int i = 0; i < 4; i++) af[i]  = *(const bf16x8*)(&As[wm + i * 16 + mr][qk]);
#pragma unroll
        for (int j = 0; j < 4; j++) bfr[j] = *(const bf16x8*)(&Bs[wn + j * 16 + mr][qk]);
#pragma unroll
        for (int i = 0; i < 4; i++)
#pragma unroll
            for (int j = 0; j < 4; j++)
                acc[i][j] = __builtin_amdgcn_mfma_f32_16x16x32_bf16(af[i], bfr[j], acc[i][j], 0, 0, 0);
        __syncthreads();
    }

    const int cr = (lane >> 4) * 4;
    const int cc = lane & 15;
#pragma unroll
    for (int i = 0; i < 4; i++) {
#pragma unroll
        for (int j = 0; j < 4; j++) {
            const long m = m0 + wm + i * 16 + cr;
            const long n = n0 + wn + j * 16 + cc;
#pragma unroll
            for (int r = 0; r < 4; r++) C[(m + r) * ldc + n] = f2bf(acc[i][j][r]);
        }
    }
}

// ---------------------------------------------------------------------------
// Fused: in-place L2-normalize q (x 1/16) and k per head; beta & dec per head.
// ---------------------------------------------------------------------------
__global__ __launch_bounds__(1024) void norm_beta_kernel(
    const u16* __restrict__ xb, u16* __restrict__ Y,
    const float* __restrict__ Wb, const float* __restrict__ Wa,
    const float* __restrict__ A_log, const float* __restrict__ dt_bias,
    float* __restrict__ beta, float* __restrict__ dec) {
    const long row = blockIdx.x;
    const int c = threadIdx.x;
    const int h = c >> 8;
    float qv = bf2f(Y[row * 3072 + c]);
    float kv = bf2f(Y[row * 3072 + 1024 + c]);
    float xv = bf2f(xb[row * 1024 + c]);
    float vals[10];
    vals[0] = qv * qv;
    vals[1] = kv * kv;
#pragma unroll
    for (int hh = 0; hh < 4; hh++) vals[2 + hh] = xv * Wb[c * 4 + hh];
#pragma unroll
    for (int hh = 0; hh < 4; hh++) vals[6 + hh] = xv * Wa[c * 4 + hh];
#pragma unroll
    for (int i = 0; i < 10; i++)
        for (int off = 32; off; off >>= 1) vals[i] += __shfl_xor(vals[i], off, 64);

    __shared__ float wred[16][10];
    __shared__ float sQ[4], sK[4];
    const int w = c >> 6;
    if ((c & 63) == 0) {
#pragma unroll
        for (int i = 0; i < 10; i++) wred[w][i] = vals[i];
    }
    __syncthreads();
    if (c < 4) {
        float s = wred[c * 4 + 0][0] + wred[c * 4 + 1][0] + wred[c * 4 + 2][0] + wred[c * 4 + 3][0];
        sQ[c] = rsqrtf(s + 1e-6f) * 0.0625f;
    } else if (c < 8) {
        int hh = c - 4;
        float s = wred[hh * 4 + 0][1] + wred[hh * 4 + 1][1] + wred[hh * 4 + 2][1] + wred[hh * 4 + 3][1];
        sK[hh] = rsqrtf(s + 1e-6f);
    } else if (c < 12) {
        int hh = c - 8;
        float s = 0.f;
        for (int ww = 0; ww < 16; ww++) s += wred[ww][2 + hh];
        beta[row * 4 + hh] = 1.f / (1.f + expf(-s));
    } else if (c < 16) {
        int hh = c - 12;
        float s = 0.f;
        for (int ww = 0; ww < 16; ww++) s += wred[ww][6 + hh];
        float z = s + dt_bias[hh];
        float sp = (z > 0.f) ? (z + log1pf(expf(-z))) : log1pf(expf(z));
        dec[row * 4 + hh] = expf(-expf(A_log[hh]) * sp);
    }
    __syncthreads();
    Y[row * 3072 + c]        = f2bf(qv * sQ[h]);
    Y[row * 3072 + 1024 + c] = f2bf(kv * sK[h]);
}

// ---------------------------------------------------------------------------
// PASS A (chunk-parallel prep): per (bh, chunk) compute A matrix, T=(I+A)^-1
// via nilpotent doubling, and M matrix. Writes T, M (bf16 [64][64]) to global.
// Grid 1024 = bh(16) x chunk(64). LDS 78 KB -> 2 blocks/CU.
// ---------------------------------------------------------------------------
__global__ __launch_bounds__(256) void prep_kernel(const u16* __restrict__ Y,
                                                   const float* __restrict__ beta,
                                                   const float* __restrict__ dec,
                                                   u16* __restrict__ Tg,
                                                   u16* __restrict__ Mg) {
    __shared__ __attribute__((aligned(16))) u16 lds[38400];
    __shared__ float sf[320];
    u16* KS  = lds;            // 64 x 264
    u16* QS  = lds + 16896;    // 64 x 264
    u16* AM  = lds + 33792;    // 64 x 72
    // overlays (valid after G phase; KS/QS dead):
    u16* Tm  = lds;            // 64 x 72
    u16* AMT = lds + 4608;
    u16* MP  = lds + 9216;
    u16* MPT = lds + 13824;

    const int bx = blockIdx.x;
    const int bh = bx >> 6, c = bx & 63;
    const int b = bh >> 2, h = bh & 3;
    const int tid = threadIdx.x, lane = tid & 63, wv = tid >> 6;
    const int quad = lane >> 4, l15 = lane & 15;
    const int tld = tid >> 2, seg = tid & 3;
    const long bt0 = (long)b * 4096 + c * 64;
    u16* Tc = Tg + (size_t)(bh * 64 + c) * 4096;
    u16* Mc = Mg + (size_t)(bh * 64 + c) * 4096;
    const f32x4 z4 = {0.f, 0.f, 0.f, 0.f};

    // ---- stage K,Q; gamma prefix ----
    {
        const long rb = (bt0 + tld) * 3072 + h * 256 + seg * 64;
#pragma unroll
        for (int i = 0; i < 8; i++) {
            *(u16x8*)&KS[tld * 264 + seg * 64 + i * 8] = *(const u16x8*)&Y[rb + 1024 + i * 8];
            *(u16x8*)&QS[tld * 264 + seg * 64 + i * 8] = *(const u16x8*)&Y[rb + i * 8];
        }
    }
    if (wv == 0) {
        float d   = dec [(bt0 + lane) * 4 + h];
        float bt_ = beta[(bt0 + lane) * 4 + h];
        float lg = log2f(fmaxf(d, 1e-30f));
#pragma unroll
        for (int off = 1; off < 64; off <<= 1) {
            float o = __shfl_up(lg, off, 64);
            if (lane >= off) lg += o;
        }
        sf[lane] = lg; sf[192 + lane] = bt_;
    }
    __syncthreads();   // B1

    // ---- G phase: waves 0-1 -> A matrix (LDS); waves 2-3 -> M (global) ----
    {
        const u16* Ab = (wv < 2) ? KS : QS;
        const int mb = (wv & 1) * 32;
        f32x4 g[2][4];
#pragma unroll
        for (int mi = 0; mi < 2; mi++)
#pragma unroll
            for (int sj = 0; sj < 4; sj++) g[mi][sj] = z4;
#pragma unroll 2
        for (int k0 = 0; k0 < 256; k0 += 32) {
            bf16x8 bfr[4];
#pragma unroll
            for (int sj = 0; sj < 4; sj++) bfr[sj] = ldfrag(KS, 264, sj * 16, k0, lane);
#pragma unroll
            for (int mi = 0; mi < 2; mi++) {
                bf16x8 af = ldfrag(Ab, 264, mb + mi * 16, k0, lane);
#pragma unroll
                for (int sj = 0; sj < 4; sj++)
                    g[mi][sj] = __builtin_amdgcn_mfma_f32_16x16x32_bf16(af, bfr[sj], g[mi][sj], 0, 0, 0);
            }
        }
#pragma unroll
        for (int mi = 0; mi < 2; mi++)
#pragma unroll
            for (int sj = 0; sj < 4; sj++)
#pragma unroll
                for (int r = 0; r < 4; r++) {
                    const int t_ = mb + mi * 16 + quad * 4 + r, s_ = sj * 16 + l15;
                    if (wv < 2)
                        AM[t_ * 72 + s_] = (s_ < t_) ? f2bf(sf[192 + t_] * exp2f(sf[t_] - sf[s_]) * g[mi][sj][r]) : (u16)0;
                    else
                        Mc[t_ * 64 + s_] = (s_ <= t_) ? f2bf(exp2f(sf[t_] - sf[s_]) * g[mi][sj][r]) : (u16)0;
                }
    }
    __syncthreads();   // B2 (KS/QS dead)

    // ---- solve init: T = I - A, A^T ----
    {
        const int t_ = tid >> 2;
#pragma unroll
        for (int i = 0; i < 16; i++) {
            const int s_ = (tid & 3) * 16 + i;
            const u16 a = AM[t_ * 72 + s_];
            Tm[t_ * 72 + s_] = (t_ == s_) ? (u16)0x3F80 : (u16)(a ^ 0x8000);
            AMT[s_ * 72 + t_] = a;
        }
    }
    __syncthreads();   // B3

    // ---- r1: Mp = N*N ----
    {
        f32x4 sq[4];
#pragma unroll
        for (int sj = 0; sj < 4; sj++) sq[sj] = z4;
#pragma unroll
        for (int k0 = 0; k0 < 64; k0 += 32) {
            bf16x8 a = ldfrag(AM, 72, 16 * wv, k0, lane);
#pragma unroll
            for (int sj = 0; sj < 4; sj++) {
                bf16x8 bb = ldfrag(AMT, 72, sj * 16, k0, lane);
                sq[sj] = __builtin_amdgcn_mfma_f32_16x16x32_bf16(a, bb, sq[sj], 0, 0, 0);
            }
        }
#pragma unroll
        for (int sj = 0; sj < 4; sj++)
#pragma unroll
            for (int r = 0; r < 4; r++) {
                const int t_ = 16 * wv + quad * 4 + r, s_ = sj * 16 + l15;
                const u16 vbf = f2bf(sq[sj][r]);
                MP[t_ * 72 + s_] = vbf;
                MPT[s_ * 72 + t_] = vbf;
            }
        __syncthreads();   // B4
    }

    // ---- fused rounds: T += T*Mp ; Mp <- Mp*Mp (skip on last) ----
#pragma unroll 1
    for (int jj = 0; jj < 5; jj++) {
        const bool last = (jj == 4);
        f32x4 pp[4], sq[4];
#pragma unroll
        for (int sj = 0; sj < 4; sj++) {
            sq[sj] = z4;
#pragma unroll
            for (int r = 0; r < 4; r++)
                pp[sj][r] = bf2f(Tm[(16 * wv + quad * 4 + r) * 72 + sj * 16 + l15]);
        }
#pragma unroll
        for (int k0 = 0; k0 < 64; k0 += 32) {
            bf16x8 at = ldfrag(Tm, 72, 16 * wv, k0, lane);
            bf16x8 am = ldfrag(MP, 72, 16 * wv, k0, lane);
#pragma unroll
            for (int sj = 0; sj < 4; sj++) {
                bf16x8 bb = ldfrag(MPT, 72, sj * 16, k0, lane);
                pp[sj] = __builtin_amdgcn_mfma_f32_16x16x32_bf16(at, bb, pp[sj], 0, 0, 0);
                if (!last) sq[sj] = __builtin_amdgcn_mfma_f32_16x16x32_bf16(am, bb, sq[sj], 0, 0, 0);
            }
        }
        __syncthreads();
#pragma unroll
        for (int sj = 0; sj < 4; sj++)
#pragma unroll
            for (int r = 0; r < 4; r++) {
                const int t_ = 16 * wv + quad * 4 + r, s_ = sj * 16 + l15;
                Tm[t_ * 72 + s_] = f2bf(pp[sj][r]);
                if (!last) {
                    const u16 vbf = f2bf(sq[sj][r]);
                    MP[t_ * 72 + s_] = vbf;
                    MPT[s_ * 72 + t_] = vbf;
                }
            }
        __syncthreads();
    }

    // ---- write T to global ----
    {
        const int t_ = tid >> 2;
#pragma unroll
        for (int i = 0; i < 16; i++) {
            const int s_ = (tid & 3) * 16 + i;
            Tc[t_ * 64 + s_] = Tm[t_ * 72 + s_];
        }
    }
}

// ---------------------------------------------------------------------------
// PASS B (sequential scan): grid 64 = bh(16) x dvs(4). Per chunk:
// P=K*S0, Pq=Q*S0; RHS = beta*V - beta*gam*P; U = T*RHS;
// O = gam*Pq + M*U; S <- gamL*S + K'^T U.  T/M/K/Q/V read from global.
// ---------------------------------------------------------------------------
__global__ __launch_bounds__(256) void scan_kernel(const u16* __restrict__ Y,
                                                   const float* __restrict__ beta,
                                                   const float* __restrict__ dec,
                                                   const u16* __restrict__ Tg,
                                                   const u16* __restrict__ Mg,
                                                   u16* __restrict__ Ob) {
    // KT: 4 panels of [64dk][72t] with +8-row pad between panels so the
    // seg-jump (2308 words) is != 0 mod 32 banks -> conflict-free writes.
    __shared__ __attribute__((aligned(16))) u16 KT[4 * 4616];
    __shared__ __attribute__((aligned(16))) u16 ST[64 * 264];
    __shared__ __attribute__((aligned(16))) u16 RHST[64 * 72];
    __shared__ __attribute__((aligned(16))) u16 UT[64 * 72];
    __shared__ float sf[320];  // [0]=lg, [64]=gam, [128]=beta*gam, [192]=beta, [256]=gamL/gam

    const int bx = blockIdx.x;
    const int bh = bx >> 2, dvs = bx & 3;
    const int b = bh >> 2, h = bh & 3;
    const int tid = threadIdx.x, lane = tid & 63, wv = tid >> 6;
    const int quad = lane >> 4, l15 = lane & 15;
    const int tld = tid >> 2, seg = tid & 3;
    const f32x4 z4 = {0.f, 0.f, 0.f, 0.f};

    f32x4 Sacc[4][4];   // [dv-tile i][dk-tile j] within wave's 64-dk slice
#pragma unroll
    for (int i = 0; i < 4; i++)
#pragma unroll
        for (int j = 0; j < 4; j++) Sacc[i][j] = z4;
    for (int i = tid; i < 64 * 264; i += 256) ST[i] = 0;
    __syncthreads();

#pragma unroll 1
    for (int c = 0; c < 64; ++c) {
        const long bt0 = (long)b * 4096 + c * 64;
        const u16* Tc = Tg + (size_t)(bh * 64 + c) * 4096;
        const u16* Mc = Mg + (size_t)(bh * 64 + c) * 4096;
        const u16* Kg = Y + bt0 * 3072 + 1024 + h * 256;   // [t][dk] stride 3072
        const u16* Qg = Y + bt0 * 3072 + h * 256;

        if (wv == 0) {
            float d   = dec [(bt0 + lane) * 4 + h];
            float bt_ = beta[(bt0 + lane) * 4 + h];
            float lg = log2f(fmaxf(d, 1e-30f));
#pragma unroll
            for (int off = 1; off < 64; off <<= 1) {
                float o = __shfl_up(lg, off, 64);
                if (lane >= off) lg += o;
            }
            float lgL = __shfl(lg, 63, 64);
            float g = exp2f(lg);
            sf[lane] = lg; sf[64 + lane] = g; sf[128 + lane] = bt_ * g;
            sf[192 + lane] = bt_; sf[256 + lane] = exp2f(lgL - lg);
        }
        __syncthreads();   // B1

        // ---- KT build (off critical path; read by S phase after B2) ----
        {
            const float ksc = sf[256 + tld];
            const u16* kr = Kg + (size_t)tld * 3072 + seg * 64;
#pragma unroll
            for (int i = 0; i < 8; i++) {
                u16x8 kv = *(const u16x8*)(kr + i * 8);
#pragma unroll
                for (int j2 = 0; j2 < 8; j2++)
                    KT[seg * 4616 + (i * 8 + j2) * 72 + tld] = f2bf(ksc * bf2f(kv[j2]));
            }
        }

        // ---- P phase: pk = K*S0, pq = Q*S0 (A from global, B=ST) ----
        f32x4 pk[4], pq[4], oacc[4];
#pragma unroll
        for (int j = 0; j < 4; j++) { pk[j] = z4; pq[j] = z4; }
#pragma unroll 2
        for (int k0 = 0; k0 < 256; k0 += 32) {
            bf16x8 sfr[4];
#pragma unroll
            for (int j = 0; j < 4; j++) sfr[j] = ldfrag(ST, 264, j * 16, k0, lane);
            bf16x8 ak = ldfrag(Kg, 3072, 16 * wv, k0, lane);
            bf16x8 aq = ldfrag(Qg, 3072, 16 * wv, k0, lane);
#pragma unroll
            for (int j = 0; j < 4; j++) {
                pk[j] = __builtin_amdgcn_mfma_f32_16x16x32_bf16(ak, sfr[j], pk[j], 0, 0, 0);
                pq[j] = __builtin_amdgcn_mfma_f32_16x16x32_bf16(aq, sfr[j], pq[j], 0, 0, 0);
            }
        }
#pragma unroll
        for (int j = 0; j < 4; j++)
#pragma unroll
            for (int r = 0; r < 4; r++) {
                const int t_ = 16 * wv + quad * 4 + r;
                const float v = bf2f(Y[(bt0 + t_) * 3072 + 2048 + h * 256 + dvs * 64 + j * 16 + l15]);
                const float rhs = sf[192 + t_] * v - sf[128 + t_] * pk[j][r];
                RHST[(j * 16 + l15) * 72 + t_] = f2bf(rhs);
                oacc[j][r] = sf[64 + t_] * pq[j][r];
            }
        __syncthreads();   // B2 (RHST + KT visible)

        // ---- U = T * RHS -> UT ----
        {
            f32x4 uu[4];
#pragma unroll
            for (int sj = 0; sj < 4; sj++) uu[sj] = z4;
#pragma unroll
            for (int k0 = 0; k0 < 64; k0 += 32) {
                bf16x8 at = ldfrag(Tc, 64, 16 * wv, k0, lane);
#pragma unroll
                for (int sj = 0; sj < 4; sj++) {
                    bf16x8 bb = ldfrag(RHST, 72, sj * 16, k0, lane);
                    uu[sj] = __builtin_amdgcn_mfma_f32_16x16x32_bf16(at, bb, uu[sj], 0, 0, 0);
                }
            }
#pragma unroll
            for (int sj = 0; sj < 4; sj++)
#pragma unroll
                for (int r = 0; r < 4; r++)
                    UT[(sj * 16 + l15) * 72 + (16 * wv + quad * 4 + r)] = f2bf(uu[sj][r]);
        }
        __syncthreads();   // B3

        // ---- O = oacc + M*U -> global; S update; write ST ----
        {
#pragma unroll
            for (int k0 = 0; k0 < 64; k0 += 32) {
                bf16x8 am = ldfrag(Mc, 64, 16 * wv, k0, lane);
#pragma unroll
                for (int sj = 0; sj < 4; sj++) {
                    bf16x8 bb = ldfrag(UT, 72, sj * 16, k0, lane);
                    oacc[sj] = __builtin_amdgcn_mfma_f32_16x16x32_bf16(am, bb, oacc[sj], 0, 0, 0);
                }
            }
#pragma unroll
            for (int sj = 0; sj < 4; sj++)
#pragma unroll
                for (int r = 0; r < 4; r++) {
                    const int t_ = 16 * wv + quad * 4 + r;
                    Ob[((long)b * 4096 + c * 64 + t_) * 1024 + h * 256 + dvs * 64 + sj * 16 + l15] = f2bf(oacc[sj][r]);
                }
            const float gL = sf[64 + 63];
#pragma unroll
            for (int i = 0; i < 4; i++)
#pragma unroll
                for (int j = 0; j < 4; j++) Sacc[i][j] *= gL;
            const u16* KTp = KT + wv * 4616;
#pragma unroll
            for (int k0 = 0; k0 < 64; k0 += 32) {
                bf16x8 au[4], bk[4];
#pragma unroll
                for (int i = 0; i < 4; i++) au[i] = ldfrag(UT, 72, i * 16, k0, lane);
#pragma unroll
                for (int j = 0; j < 4; j++) bk[j] = ldfrag(KTp, 72, j * 16, k0, lane);
#pragma unroll
                for (int i = 0; i < 4; i++)
#pragma unroll
                    for (int j = 0; j < 4; j++)
                        Sacc[i][j] = __builtin_amdgcn_mfma_f32_16x16x32_bf16(au[i], bk[j], Sacc[i][j], 0, 0, 0);
            }
#pragma unroll
            for (int i = 0; i < 4; i++)
#pragma unroll
                for (int j = 0; j < 4; j++)
#pragma unroll
                    for (int r = 0; r < 4; r++)
                        ST[(i * 16 + quad * 4 + r) * 264 + wv * 64 + j * 16 + l15] = f2bf(Sacc[i][j][r]);
        }
        __syncthreads();   // B4
    }
}

// ---------------------------------------------------------------------------
// Gated RMSNorm + SiLU; writes og IN PLACE into G.
// ---------------------------------------------------------------------------
__global__ __launch_bounds__(256) void gate_norm_kernel(const u16* __restrict__ O,
                                                        u16* __restrict__ G,
                                                        const float* __restrict__ norm_w) {
    const long row = blockIdx.x >> 2;
    const int h = blockIdx.x & 3;
    const int dv = threadIdx.x;
    const long idx = row * 1024 + h * 256 + dv;
    float o = bf2f(O[idx]);
    float s = o * o;
#pragma unroll
    for (int off = 32; off; off >>= 1) s += __shfl_xor(s, off, 64);
    __shared__ float wsum[4];
    if ((dv & 63) == 0) wsum[dv >> 6] = s;
    __syncthreads();
    const float tot = wsum[0] + wsum[1] + wsum[2] + wsum[3];
    const float r = rsqrtf(tot * (1.f / 256.f) + 1e-5f);
    const float g = bf2f(G[idx]);
    const float val = o * r * norm_w[dv] * (g / (1.f + expf(-g)));
    G[idx] = f2bf(val);
}

// ---------------------------------------------------------------------------
extern "C" void kernel_launch(void* const* d_in, const int* in_sizes, int n_in,
                              void* d_out, int out_size, void* d_ws, size_t ws_size,
                              hipStream_t stream) {
    const float* x       = (const float*)d_in[0];
    const float* Wq      = (const float*)d_in[1];
    const float* Wk      = (const float*)d_in[2];
    const float* Wv      = (const float*)d_in[3];
    const float* Wb      = (const float*)d_in[4];
    const float* Wa      = (const float*)d_in[5];
    const float* A_log   = (const float*)d_in[6];
    const float* dt_bias = (const float*)d_in[7];
    const float* Wg      = (const float*)d_in[8];
    const float* norm_w  = (const float*)d_in[9];
    const float* Wo      = (const float*)d_in[10];

    // workspace: identical 171 MB footprint as round 3/4 (proven to fit).
    char* p = (char*)d_ws;
    u16*   WT   = (u16*)p;   p += (size_t)5120 * 1024 * 2;   // WqT|WkT|WvT|WgT|WoT bf16
    u16*   Y    = (u16*)p;   p += (size_t)16384 * 3072 * 2;  // q|k|v bf16
    u16*   G    = (u16*)p;   p += (size_t)16384 * 1024 * 2;  // T|M (prep+scan), then gate/og
    u16*   XO   = (u16*)p;   p += (size_t)16384 * 1024 * 2;  // xb (early), O (scan output)
    float* beta = (float*)p; p += (size_t)16384 * 4 * 4;
    float* dec  = (float*)p; p += (size_t)16384 * 4 * 4;

    u16* Tg = G;                                  // [16*64][64*64] bf16, 8.4 MB
    u16* Mg = G + (size_t)1024 * 4096;            // same, next 8.4 MB

    cvt_kernel<<<16384, 256, 0, stream>>>(x, XO);

    dim3 tb(32, 8), tg(32, 32);
    transpose_kernel<<<tg, tb, 0, stream>>>(Wq, WT + (size_t)0 * 1024 * 1024);
    transpose_kernel<<<tg, tb, 0, stream>>>(Wk, WT + (size_t)1 * 1024 * 1024);
    transpose_kernel<<<tg, tb, 0, stream>>>(Wv, WT + (size_t)2 * 1024 * 1024);
    transpose_kernel<<<tg, tb, 0, stream>>>(Wg, WT + (size_t)3 * 1024 * 1024);
    transpose_kernel<<<tg, tb, 0, stream>>>(Wo, WT + (size_t)4 * 1024 * 1024);

    // Y = xb @ [Wq|Wk|Wv]   (M=16384, N=3072, K=1024)
    gemm_kernel<0><<<dim3(3072 / 128, 16384 / 128), 256, 0, stream>>>(
        XO, WT, (void*)Y, 16384, 3072, 1024, 3072);

    norm_beta_kernel<<<16384, 1024, 0, stream>>>(XO, Y, Wb, Wa, A_log, dt_bias, beta, dec);

    prep_kernel<<<1024, 256, 0, stream>>>(Y, beta, dec, Tg, Mg);

    // xb dead; scan writes O into XO
    scan_kernel<<<64, 256, 0, stream>>>(Y, beta, dec, Tg, Mg, XO);

    // gate = x @ Wg (fp32 A read directly; overwrites T/M region -> after scan)
    gemm_a32_kernel<<<dim3(1024 / 128, 16384 / 128), 256, 0, stream>>>(
        x, WT + (size_t)3072 * 1024, G, 16384, 1024, 1024, 1024);

    gate_norm_kernel<<<16384 * 4, 256, 0, stream>>>(XO, G, norm_w);

    // out = og @ Wo   (fp32 out)
    gemm_kernel<1><<<dim3(1024 / 128, 16384 / 128), 256, 0, stream>>>(
        G, WT + (size_t)4096 * 1024, d_out, 16384, 1024, 1024, 1024);
}